// Round 1
// baseline (575.308 us; speedup 1.0000x reference)
//
#include <hip/hip_runtime.h>
#include <hip/hip_bf16.h>

typedef _Float16 f16x8 __attribute__((ext_vector_type(8)));
typedef _Float16 f16x4 __attribute__((ext_vector_type(4)));
typedef float f32x4 __attribute__((ext_vector_type(4)));

typedef __attribute__((address_space(1))) void GV;
typedef __attribute__((address_space(3))) void LV;

__device__ inline void async16(void* lds, const void* g) {
    __builtin_amdgcn_global_load_lds((GV*)g, (LV*)lds, 16, 0, 0);
}

// ---------------- cast f32 -> f16 ----------------
__global__ __launch_bounds__(256) void cast_kernel(const float* __restrict__ in,
                                                   _Float16* __restrict__ out, long n4) {
    long i = (long)blockIdx.x * blockDim.x + threadIdx.x;
    if (i < n4) {
        float4 v = ((const float4*)in)[i];
        f16x4 o;
        o[0] = (_Float16)v.x; o[1] = (_Float16)v.y;
        o[2] = (_Float16)v.z; o[3] = (_Float16)v.w;
        ((f16x4*)out)[i] = o;
    }
}

// ---------------- V transpose: in [b][s][e] -> out [b][e][s] ----------------
__global__ __launch_bounds__(256) void transpose_v(const _Float16* __restrict__ in,
                                                   _Float16* __restrict__ out) {
    __shared__ _Float16 tile[64][66];
    int b = blockIdx.z;
    long base = (long)b * 1048576;
    int s0 = blockIdx.x * 64, e0 = blockIdx.y * 64;
    int tc = threadIdx.x & 63, tr = threadIdx.x >> 6;  // tr in 0..3
    #pragma unroll
    for (int rr = 0; rr < 64; rr += 4)
        tile[tr + rr][tc] = in[base + (long)(s0 + tr + rr) * 1024 + e0 + tc];
    __syncthreads();
    #pragma unroll
    for (int rr = 0; rr < 64; rr += 4)
        out[base + (long)(e0 + tr + rr) * 1024 + s0 + tc] = tile[tc][tr + rr];
}

// ---------------- batched GEMM: C = A @ B^T, f32 accum ----------------
// A: (M x K) rows at lda, B: (N x K) rows at ldb, C: (M x N) at ldc.
// Per-z offsets: offA=(z/az_div)*sa_hi+(z%az_div)*sa_lo; offB=z*sb;
//                offC=(z/cz_div)*sc_hi+(z%cz_div)*sc_lo.
__global__ __launch_bounds__(256) void gemm_bt(
    const _Float16* __restrict__ A0, const _Float16* __restrict__ B0, void* __restrict__ C0,
    int K, int lda, int ldb, int ldc,
    int az_div, long sa_hi, long sa_lo, long sb,
    int cz_div, long sc_hi, long sc_lo, int out_f32)
{
    __shared__ _Float16 As[128 * 64];
    __shared__ _Float16 Bs[128 * 64];
    int z = blockIdx.z;
    const _Float16* A = A0 + (long)(z / az_div) * sa_hi + (long)(z % az_div) * sa_lo;
    const _Float16* B = B0 + (long)z * sb;
    long coff = (long)(z / cz_div) * sc_hi + (long)(z % cz_div) * sc_lo;
    int rowbase = blockIdx.y * 128, colbase = blockIdx.x * 128;
    int t = threadIdx.x, wave = t >> 6, lane = t & 63;
    int l15 = lane & 15, lg = lane >> 4;
    int srow = t >> 3, scol = (t & 7) * 8;
    int wm = wave >> 1, wn = wave & 1;
    f32x4 acc[4][4] = {};
    for (int k0 = 0; k0 < K; k0 += 64) {
        #pragma unroll
        for (int ii = 0; ii < 4; ii++) {
            int r = srow + ii * 32;
            async16(&As[r * 64 + scol], A + (long)(rowbase + r) * lda + k0 + scol);
            async16(&Bs[r * 64 + scol], B + (long)(colbase + r) * ldb + k0 + scol);
        }
        __syncthreads();
        #pragma unroll
        for (int ks = 0; ks < 2; ks++) {
            f16x8 af[4], bfr[4];
            #pragma unroll
            for (int m = 0; m < 4; m++)
                af[m] = *(const f16x8*)&As[(wm * 64 + m * 16 + l15) * 64 + ks * 32 + lg * 8];
            #pragma unroll
            for (int n = 0; n < 4; n++)
                bfr[n] = *(const f16x8*)&Bs[(wn * 64 + n * 16 + l15) * 64 + ks * 32 + lg * 8];
            #pragma unroll
            for (int m = 0; m < 4; m++)
                #pragma unroll
                for (int n = 0; n < 4; n++)
                    acc[m][n] = __builtin_amdgcn_mfma_f32_16x16x32_f16(af[m], bfr[n], acc[m][n], 0, 0, 0);
        }
        __syncthreads();
    }
    #pragma unroll
    for (int m = 0; m < 4; m++) {
        int row = rowbase + wm * 64 + m * 16 + lg * 4;
        #pragma unroll
        for (int n = 0; n < 4; n++) {
            int col = colbase + wn * 64 + n * 16 + l15;
            #pragma unroll
            for (int r = 0; r < 4; r++) {
                long idx = coff + (long)(row + r) * ldc + col;
                if (out_f32) ((float*)C0)[idx] = acc[m][n][r];
                else ((_Float16*)C0)[idx] = (_Float16)acc[m][n][r];
            }
        }
    }
}

// ---------------- fused QK^T + softmax + mean over i ----------------
// Block: (t-tile of 16 rows, h, b); 4 waves each own 256 cols of s.
// Loops outer head i internally, accumulating mean_i softmax in registers.
__global__ __launch_bounds__(256) void attn_softmax(
    const _Float16* __restrict__ Qbuf, const _Float16* __restrict__ Kbuf,
    float* __restrict__ attn_out, _Float16* __restrict__ Pbar)
{
    __shared__ float red[4][16];
    int t0 = blockIdx.x * 16;
    int h = blockIdx.y, b = blockIdx.z;
    int tid = threadIdx.x, wave = tid >> 6, lane = tid & 63;
    int l15 = lane & 15, lg = lane >> 4;
    const float scale = 0.088388347648318447f;  // 1/sqrt(128)
    float acc[16][4];
    #pragma unroll
    for (int ct = 0; ct < 16; ct++)
        #pragma unroll
        for (int r = 0; r < 4; r++) acc[ct][r] = 0.f;

    for (int i = 0; i < 8; i++) {
        const _Float16* Qb = Qbuf + ((long)(i * 2 + b) * 1024 + t0) * 1024 + h * 128;
        const _Float16* Kb = Kbuf + ((long)(i * 2 + b) * 1024 + wave * 256) * 1024 + h * 128;
        f16x8 aq[4];
        #pragma unroll
        for (int kk = 0; kk < 4; kk++)
            aq[kk] = *(const f16x8*)&Qb[(long)l15 * 1024 + kk * 32 + lg * 8];
        f32x4 s[16];
        #pragma unroll
        for (int ct = 0; ct < 16; ct++) {
            f32x4 sv = {0.f, 0.f, 0.f, 0.f};
            #pragma unroll
            for (int kk = 0; kk < 4; kk++) {
                f16x8 bk = *(const f16x8*)&Kb[(long)(ct * 16 + l15) * 1024 + kk * 32 + lg * 8];
                sv = __builtin_amdgcn_mfma_f32_16x16x32_f16(aq[kk], bk, sv, 0, 0, 0);
            }
            s[ct] = sv * scale;
        }
        // row max (rows = lg*4 + r)
        float m0[4] = {-1e30f, -1e30f, -1e30f, -1e30f};
        #pragma unroll
        for (int ct = 0; ct < 16; ct++)
            #pragma unroll
            for (int r = 0; r < 4; r++) m0[r] = fmaxf(m0[r], s[ct][r]);
        #pragma unroll
        for (int off = 1; off < 16; off <<= 1)
            #pragma unroll
            for (int r = 0; r < 4; r++) m0[r] = fmaxf(m0[r], __shfl_xor(m0[r], off, 64));
        if (l15 == 0) {
            #pragma unroll
            for (int r = 0; r < 4; r++) red[wave][lg * 4 + r] = m0[r];
        }
        __syncthreads();
        #pragma unroll
        for (int r = 0; r < 4; r++) {
            int row = lg * 4 + r;
            m0[r] = fmaxf(fmaxf(red[0][row], red[1][row]), fmaxf(red[2][row], red[3][row]));
        }
        __syncthreads();
        // exp + sum
        float sum[4] = {0.f, 0.f, 0.f, 0.f};
        #pragma unroll
        for (int ct = 0; ct < 16; ct++)
            #pragma unroll
            for (int r = 0; r < 4; r++) {
                float e = __expf(s[ct][r] - m0[r]);
                s[ct][r] = e;
                sum[r] += e;
            }
        #pragma unroll
        for (int off = 1; off < 16; off <<= 1)
            #pragma unroll
            for (int r = 0; r < 4; r++) sum[r] += __shfl_xor(sum[r], off, 64);
        if (l15 == 0) {
            #pragma unroll
            for (int r = 0; r < 4; r++) red[wave][lg * 4 + r] = sum[r];
        }
        __syncthreads();
        #pragma unroll
        for (int r = 0; r < 4; r++) {
            int row = lg * 4 + r;
            sum[r] = 0.125f / (red[0][row] + red[1][row] + red[2][row] + red[3][row]);
        }
        __syncthreads();
        #pragma unroll
        for (int ct = 0; ct < 16; ct++)
            #pragma unroll
            for (int r = 0; r < 4; r++) acc[ct][r] += s[ct][r] * sum[r];
    }
    long base = ((long)((b * 8 + h) * 1024 + t0)) * 1024 + wave * 256;
    #pragma unroll
    for (int ct = 0; ct < 16; ct++)
        #pragma unroll
        for (int r = 0; r < 4; r++) {
            long idx = base + (long)(lg * 4 + r) * 1024 + ct * 16 + l15;
            float v = acc[ct][r];
            attn_out[idx] = v;
            Pbar[idx] = (_Float16)v;
        }
}

extern "C" void kernel_launch(void* const* d_in, const int* in_sizes, int n_in,
                              void* d_out, int out_size, void* d_ws, size_t ws_size,
                              hipStream_t stream) {
    const long M1 = 1048576;
    _Float16* ws = (_Float16*)d_ws;
    _Float16* q16  = ws;             // 2M elts
    _Float16* wq16 = ws + 6 * M1;    // 8M (Wk follows contiguously at +14M)
    _Float16* wv16 = ws + 22 * M1;   // 1M
    _Float16* wo16 = ws + 23 * M1;   // 1M
    _Float16* Qbuf = ws + 24 * M1;   // 16M (Kbuf follows at +40M)
    _Float16* Vbuf = ws + 56 * M1;   // 2M
    _Float16* Vt   = ws + 58 * M1;   // 2M
    _Float16* Pb   = ws + 60 * M1;   // 16M
    _Float16* Hbar = ws + 76 * M1;   // 2M
    float* out = (float*)d_out;
    float* attn_out = out + 2 * M1;

    // casts: query,key,value -> q16[0,2M,4M); Wq,Wk -> wq16 (16M); Wv,Wo
    cast_kernel<<<2048, 256, 0, stream>>>((const float*)d_in[0], q16, 2 * M1 / 4);
    cast_kernel<<<2048, 256, 0, stream>>>((const float*)d_in[1], q16 + 2 * M1, 2 * M1 / 4);
    cast_kernel<<<2048, 256, 0, stream>>>((const float*)d_in[2], q16 + 4 * M1, 2 * M1 / 4);
    cast_kernel<<<8192, 256, 0, stream>>>((const float*)d_in[3], wq16, 8 * M1 / 4);
    cast_kernel<<<8192, 256, 0, stream>>>((const float*)d_in[4], wq16 + 8 * M1, 8 * M1 / 4);
    cast_kernel<<<1024, 256, 0, stream>>>((const float*)d_in[5], wv16, M1 / 4);
    cast_kernel<<<1024, 256, 0, stream>>>((const float*)d_in[6], wo16, M1 / 4);

    // Q/K projections: z=0..7 -> Q_i = query @ Wq[i]^T; z=8..15 -> K_i
    gemm_bt<<<dim3(8, 16, 16), 256, 0, stream>>>(
        q16, wq16, Qbuf, 1024, 1024, 1024, 1024,
        /*az*/ 8, 2 * M1, 0, /*sb*/ M1,
        /*cz*/ 16, 0, 2 * M1, /*f32*/ 0);
    // V projection: value @ Wv^T
    gemm_bt<<<dim3(8, 16, 1), 256, 0, stream>>>(
        q16 + 4 * M1, wv16, Vbuf, 1024, 1024, 1024, 1024,
        1, 0, 0, 0, 1, 0, 0, 0);
    // V transpose -> Vt[b][e][s]
    transpose_v<<<dim3(16, 16, 2), 256, 0, stream>>>(Vbuf, Vt);
    // fused scores+softmax+mean_i -> attention (f32) + Pbar (f16)
    attn_softmax<<<dim3(64, 8, 2), 256, 0, stream>>>(Qbuf, Qbuf + 16 * M1, attn_out, Pb);
    // PV: head[b][t][h*128+n] = sum_s Pbar[(b,h)][t][s] * Vt[b][h*128+n][s]
    gemm_bt<<<dim3(1, 8, 16), 256, 0, stream>>>(
        Pb, Vt, Hbar, 1024, 1024, 1024, 1024,
        /*az*/ 16, 0, M1, /*sb*/ M1 / 8,
        /*cz*/ 8, M1, 128, /*f32*/ 0);
    // out = head_mean @ Wo^T  (f32 out)
    gemm_bt<<<dim3(8, 16, 1), 256, 0, stream>>>(
        Hbar, wo16, out, 1024, 1024, 1024, 1024,
        1, 0, 0, 0, 1, 0, 0, /*f32*/ 1);
}

// Round 2
// 498.146 us; speedup vs baseline: 1.1549x; 1.1549x over previous
//
#include <hip/hip_runtime.h>
#include <hip/hip_bf16.h>

typedef _Float16 f16x8 __attribute__((ext_vector_type(8)));
typedef _Float16 f16x4 __attribute__((ext_vector_type(4)));
typedef float f32x4 __attribute__((ext_vector_type(4)));

typedef __attribute__((address_space(1))) void GV;
typedef __attribute__((address_space(3))) void LV;

__device__ inline void async16(void* lds, const void* g) {
    __builtin_amdgcn_global_load_lds((GV*)g, (LV*)lds, 16, 0, 0);
}

// ---------------- cast f32 -> f16 ----------------
__global__ __launch_bounds__(256) void cast_kernel(const float* __restrict__ in,
                                                   _Float16* __restrict__ out, long n4) {
    long i = (long)blockIdx.x * blockDim.x + threadIdx.x;
    if (i < n4) {
        float4 v = ((const float4*)in)[i];
        f16x4 o;
        o[0] = (_Float16)v.x; o[1] = (_Float16)v.y;
        o[2] = (_Float16)v.z; o[3] = (_Float16)v.w;
        ((f16x4*)out)[i] = o;
    }
}

// ---------------- V transpose: in [b][s][e] -> out [b][e][s] ----------------
__global__ __launch_bounds__(256) void transpose_v(const _Float16* __restrict__ in,
                                                   _Float16* __restrict__ out) {
    __shared__ _Float16 tile[64][66];
    int b = blockIdx.z;
    long base = (long)b * 1048576;
    int s0 = blockIdx.x * 64, e0 = blockIdx.y * 64;
    int tc = threadIdx.x & 63, tr = threadIdx.x >> 6;  // tr in 0..3
    #pragma unroll
    for (int rr = 0; rr < 64; rr += 4)
        tile[tr + rr][tc] = in[base + (long)(s0 + tr + rr) * 1024 + e0 + tc];
    __syncthreads();
    #pragma unroll
    for (int rr = 0; rr < 64; rr += 4)
        out[base + (long)(e0 + tr + rr) * 1024 + s0 + tc] = tile[tc][tr + rr];
}

// ---------------- batched GEMM: C = A @ B^T, f32 accum ----------------
__global__ __launch_bounds__(256) void gemm_bt(
    const _Float16* __restrict__ A0, const _Float16* __restrict__ B0, void* __restrict__ C0,
    int K, int lda, int ldb, int ldc,
    int az_div, long sa_hi, long sa_lo, long sb,
    int cz_div, long sc_hi, long sc_lo, int out_f32)
{
    __shared__ _Float16 As[128 * 64];
    __shared__ _Float16 Bs[128 * 64];
    int z = blockIdx.z;
    const _Float16* A = A0 + (long)(z / az_div) * sa_hi + (long)(z % az_div) * sa_lo;
    const _Float16* B = B0 + (long)z * sb;
    long coff = (long)(z / cz_div) * sc_hi + (long)(z % cz_div) * sc_lo;
    int rowbase = blockIdx.y * 128, colbase = blockIdx.x * 128;
    int t = threadIdx.x, wave = t >> 6, lane = t & 63;
    int l15 = lane & 15, lg = lane >> 4;
    int srow = t >> 3, scol = (t & 7) * 8;
    int wm = wave >> 1, wn = wave & 1;
    f32x4 acc[4][4] = {};
    for (int k0 = 0; k0 < K; k0 += 64) {
        #pragma unroll
        for (int ii = 0; ii < 4; ii++) {
            int r = srow + ii * 32;
            async16(&As[r * 64 + scol], A + (long)(rowbase + r) * lda + k0 + scol);
            async16(&Bs[r * 64 + scol], B + (long)(colbase + r) * ldb + k0 + scol);
        }
        __syncthreads();
        #pragma unroll
        for (int ks = 0; ks < 2; ks++) {
            f16x8 af[4], bfr[4];
            #pragma unroll
            for (int m = 0; m < 4; m++)
                af[m] = *(const f16x8*)&As[(wm * 64 + m * 16 + l15) * 64 + ks * 32 + lg * 8];
            #pragma unroll
            for (int n = 0; n < 4; n++)
                bfr[n] = *(const f16x8*)&Bs[(wn * 64 + n * 16 + l15) * 64 + ks * 32 + lg * 8];
            #pragma unroll
            for (int m = 0; m < 4; m++)
                #pragma unroll
                for (int n = 0; n < 4; n++)
                    acc[m][n] = __builtin_amdgcn_mfma_f32_16x16x32_f16(af[m], bfr[n], acc[m][n], 0, 0, 0);
        }
        __syncthreads();
    }
    #pragma unroll
    for (int m = 0; m < 4; m++) {
        int row = rowbase + wm * 64 + m * 16 + lg * 4;
        #pragma unroll
        for (int n = 0; n < 4; n++) {
            int col = colbase + wn * 64 + n * 16 + l15;
            #pragma unroll
            for (int r = 0; r < 4; r++) {
                long idx = coff + (long)(row + r) * ldc + col;
                if (out_f32) ((float*)C0)[idx] = acc[m][n][r];
                else ((_Float16*)C0)[idx] = (_Float16)acc[m][n][r];
            }
        }
    }
}

// ---------------- fused QK^T + softmax + mean over i (v2) ----------------
// 1-D grid of 1024 blocks (XCD-swizzled), 512 threads = 8 waves.
// Block covers 16 t-rows of one (b,h); wave w owns s-cols [w*128, w*128+128).
// No max-shift: scores bounded ~|10|, f32 exp is safe and softmax is
// shift-invariant. Only the row-SUM needs cross-wave reduction.
__global__ __launch_bounds__(512) void attn_softmax(
    const _Float16* __restrict__ Qbuf, const _Float16* __restrict__ Kbuf,
    float* __restrict__ attn_out, _Float16* __restrict__ Pbar)
{
    __shared__ float red[8][16];
    // XCD swizzle: physical id -> orig so XCD k gets orig [k*128,(k+1)*128)
    // = 2 complete (b,h) groups -> K slice fits its 4MB L2.
    int id = blockIdx.x;
    int orig = (id & 7) * 128 + (id >> 3);
    int t0 = (orig & 63) * 16;
    int h = (orig >> 6) & 7, b = orig >> 9;
    int tid = threadIdx.x, wave = tid >> 6, lane = tid & 63;
    int l15 = lane & 15, lg = lane >> 4;
    const float scale = 0.088388347648318447f;  // 1/sqrt(128)
    float acc[8][4] = {};

    for (int i = 0; i < 8; i++) {
        const _Float16* Qb = Qbuf + ((long)(i * 2 + b) * 1024 + t0) * 1024 + h * 128;
        const _Float16* Kb = Kbuf + ((long)(i * 2 + b) * 1024 + wave * 128) * 1024 + h * 128;
        f16x8 aq[4];
        #pragma unroll
        for (int kk = 0; kk < 4; kk++)
            aq[kk] = *(const f16x8*)&Qb[(long)l15 * 1024 + kk * 32 + lg * 8];
        f32x4 s[8];
        #pragma unroll
        for (int ct = 0; ct < 8; ct++) {
            f32x4 sv = {0.f, 0.f, 0.f, 0.f};
            #pragma unroll
            for (int kk = 0; kk < 4; kk++) {
                f16x8 bk = *(const f16x8*)&Kb[(long)(ct * 16 + l15) * 1024 + kk * 32 + lg * 8];
                sv = __builtin_amdgcn_mfma_f32_16x16x32_f16(aq[kk], bk, sv, 0, 0, 0);
            }
            s[ct] = sv;
        }
        // exp + per-lane partial row sums (rows = lg*4 + r)
        float sum[4] = {0.f, 0.f, 0.f, 0.f};
        #pragma unroll
        for (int ct = 0; ct < 8; ct++)
            #pragma unroll
            for (int r = 0; r < 4; r++) {
                float e = __expf(s[ct][r] * scale);
                s[ct][r] = e;
                sum[r] += e;
            }
        // reduce across the 16 lanes of each row group
        #pragma unroll
        for (int off = 1; off < 16; off <<= 1)
            #pragma unroll
            for (int r = 0; r < 4; r++) sum[r] += __shfl_xor(sum[r], off, 64);
        if (l15 == 0) {
            #pragma unroll
            for (int r = 0; r < 4; r++) red[wave][lg * 4 + r] = sum[r];
        }
        __syncthreads();
        float rinv[4];
        #pragma unroll
        for (int r = 0; r < 4; r++) {
            int row = lg * 4 + r;
            float tot = red[0][row] + red[1][row] + red[2][row] + red[3][row]
                      + red[4][row] + red[5][row] + red[6][row] + red[7][row];
            rinv[r] = 0.125f / tot;
        }
        __syncthreads();
        #pragma unroll
        for (int ct = 0; ct < 8; ct++)
            #pragma unroll
            for (int r = 0; r < 4; r++) acc[ct][r] += s[ct][r] * rinv[r];
    }
    long base = ((long)((b * 8 + h) * 1024 + t0)) * 1024 + wave * 128;
    #pragma unroll
    for (int ct = 0; ct < 8; ct++)
        #pragma unroll
        for (int r = 0; r < 4; r++) {
            long idx = base + (long)(lg * 4 + r) * 1024 + ct * 16 + l15;
            float v = acc[ct][r];
            attn_out[idx] = v;
            Pbar[idx] = (_Float16)v;
        }
}

extern "C" void kernel_launch(void* const* d_in, const int* in_sizes, int n_in,
                              void* d_out, int out_size, void* d_ws, size_t ws_size,
                              hipStream_t stream) {
    const long M1 = 1048576;
    _Float16* ws = (_Float16*)d_ws;
    _Float16* q16  = ws;             // 2M elts
    _Float16* wq16 = ws + 6 * M1;    // 8M (Wk follows contiguously at +14M)
    _Float16* wv16 = ws + 22 * M1;   // 1M
    _Float16* wo16 = ws + 23 * M1;   // 1M
    _Float16* Qbuf = ws + 24 * M1;   // 16M (Kbuf follows at +40M)
    _Float16* Vbuf = ws + 56 * M1;   // 2M
    _Float16* Vt   = ws + 58 * M1;   // 2M
    _Float16* Pb   = ws + 60 * M1;   // 16M
    _Float16* Hbar = ws + 76 * M1;   // 2M
    float* out = (float*)d_out;
    float* attn_out = out + 2 * M1;

    // casts: query,key,value -> q16[0,2M,4M); Wq,Wk -> wq16 (16M); Wv,Wo
    cast_kernel<<<2048, 256, 0, stream>>>((const float*)d_in[0], q16, 2 * M1 / 4);
    cast_kernel<<<2048, 256, 0, stream>>>((const float*)d_in[1], q16 + 2 * M1, 2 * M1 / 4);
    cast_kernel<<<2048, 256, 0, stream>>>((const float*)d_in[2], q16 + 4 * M1, 2 * M1 / 4);
    cast_kernel<<<8192, 256, 0, stream>>>((const float*)d_in[3], wq16, 8 * M1 / 4);
    cast_kernel<<<8192, 256, 0, stream>>>((const float*)d_in[4], wq16 + 8 * M1, 8 * M1 / 4);
    cast_kernel<<<1024, 256, 0, stream>>>((const float*)d_in[5], wv16, M1 / 4);
    cast_kernel<<<1024, 256, 0, stream>>>((const float*)d_in[6], wo16, M1 / 4);

    // Q/K projections: z=0..7 -> Q_i = query @ Wq[i]^T; z=8..15 -> K_i
    gemm_bt<<<dim3(8, 16, 16), 256, 0, stream>>>(
        q16, wq16, Qbuf, 1024, 1024, 1024, 1024,
        /*az*/ 8, 2 * M1, 0, /*sb*/ M1,
        /*cz*/ 16, 0, 2 * M1, /*f32*/ 0);
    // V projection: value @ Wv^T
    gemm_bt<<<dim3(8, 16, 1), 256, 0, stream>>>(
        q16 + 4 * M1, wv16, Vbuf, 1024, 1024, 1024, 1024,
        1, 0, 0, 0, 1, 0, 0, 0);
    // V transpose -> Vt[b][e][s]
    transpose_v<<<dim3(16, 16, 2), 256, 0, stream>>>(Vbuf, Vt);
    // fused scores+softmax+mean_i -> attention (f32) + Pbar (f16)
    attn_softmax<<<1024, 512, 0, stream>>>(Qbuf, Qbuf + 16 * M1, attn_out, Pb);
    // PV: head[b][t][h*128+n] = sum_s Pbar[(b,h)][t][s] * Vt[b][h*128+n][s]
    gemm_bt<<<dim3(1, 8, 16), 256, 0, stream>>>(
        Pb, Vt, Hbar, 1024, 1024, 1024, 1024,
        /*az*/ 16, 0, M1, /*sb*/ M1 / 8,
        /*cz*/ 8, M1, 128, /*f32*/ 0);
    // out = head_mean @ Wo^T  (f32 out)
    gemm_bt<<<dim3(8, 16, 1), 256, 0, stream>>>(
        Hbar, wo16, out, 1024, 1024, 1024, 1024,
        1, 0, 0, 0, 1, 0, 0, /*f32*/ 1);
}